// Round 1
// baseline (3816.430 us; speedup 1.0000x reference)
//
#include <hip/hip_runtime.h>

namespace {

constexpr int T_LEN = 512;

__device__ __forceinline__ float tanh_fast(float x) {
    // tanh(x) = 1 - 2/(e^{2x}+1); robust at +-inf (e=inf -> 1, e=0 -> -1)
    float e = __expf(2.0f * x);
    return 1.0f - 2.0f * __builtin_amdgcn_rcpf(e + 1.0f);
}

__global__ __launch_bounds__(256, 2)
void rnn_fused_kernel(const float* __restrict__ x,
                      const float* __restrict__ Wih0,
                      const float* __restrict__ Whh0,
                      const float* __restrict__ bih0,
                      const float* __restrict__ bhh0,
                      const float* __restrict__ Wih1,
                      const float* __restrict__ Whh1,
                      const float* __restrict__ bih1,
                      const float* __restrict__ bhh1,
                      const float* __restrict__ fc1W,
                      const float* __restrict__ fc1b,
                      const float* __restrict__ fc2W,
                      const float* __restrict__ fc2b,
                      float* __restrict__ out,
                      int B)
{
    const int lane = threadIdx.x & 63;
    const int wid  = threadIdx.x >> 6;     // wave within block (4 waves/block)
    const int b    = (blockIdx.x << 2) + wid;   // one batch element per wave
    if (b >= B) return;

    // Per-wave private LDS: ping-pong h1/h2 + x chunk. No cross-wave sharing,
    // no __syncthreads anywhere. Same-wave DS ops execute in order.
    __shared__ float sh1[4][2][64];
    __shared__ float sh2[4][2][64];
    __shared__ float sxs[4][64];

    // Lane i holds row i of each recurrent/matvec weight matrix (192 VGPRs).
    float w0[64], w1[64], w2[64];
    {
        const float4* p0 = reinterpret_cast<const float4*>(Whh0 + lane * 64);
        const float4* p1 = reinterpret_cast<const float4*>(Wih1 + lane * 64);
        const float4* p2 = reinterpret_cast<const float4*>(Whh1 + lane * 64);
#pragma unroll
        for (int j = 0; j < 16; ++j) {
            float4 v0 = p0[j];
            w0[4*j+0] = v0.x; w0[4*j+1] = v0.y; w0[4*j+2] = v0.z; w0[4*j+3] = v0.w;
            float4 v1 = p1[j];
            w1[4*j+0] = v1.x; w1[4*j+1] = v1.y; w1[4*j+2] = v1.z; w1[4*j+3] = v1.w;
            float4 v2 = p2[j];
            w2[4*j+0] = v2.x; w2[4*j+1] = v2.y; w2[4*j+2] = v2.z; w2[4*j+3] = v2.w;
        }
    }
    const float wx  = Wih0[lane];                  // D == 1
    const float bc0 = bih0[lane] + bhh0[lane];
    const float bc1 = bih1[lane] + bhh1[lane];

    // h0 = 0 in slot 0
    sh1[wid][0][lane] = 0.0f;
    sh2[wid][0][lane] = 0.0f;

    const float* xrow = x + (size_t)b * T_LEN;

    for (int t0 = 0; t0 < T_LEN; t0 += 64) {
        // stage 64 timesteps of x (coalesced 256B per wave)
        sxs[wid][lane] = xrow[t0 + lane];

#pragma unroll 2
        for (int tt = 0; tt < 64; ++tt) {
            const int t  = t0 + tt;
            const int pp = t & 1;        // prev slot
            const int cc = pp ^ 1;       // new slot
            const float xt = sxs[wid][tt];

            // --- layer0: a0 = Whh0 @ h1_prev ; layer1 partial: a2 = Whh1 @ h2_prev
            // fused j-loop for ILP; broadcast ds_read_b128 (uniform addr, conflict-free)
            float a0_0 = fmaf(xt, wx, bc0), a0_1 = 0.f, a0_2 = 0.f, a0_3 = 0.f;
            float a2_0 = bc1, a2_1 = 0.f, a2_2 = 0.f, a2_3 = 0.f;
#pragma unroll
            for (int j = 0; j < 64; j += 4) {
                float4 h2v = *reinterpret_cast<const float4*>(&sh2[wid][pp][j]);
                a2_0 = fmaf(w2[j+0], h2v.x, a2_0);
                a2_1 = fmaf(w2[j+1], h2v.y, a2_1);
                a2_2 = fmaf(w2[j+2], h2v.z, a2_2);
                a2_3 = fmaf(w2[j+3], h2v.w, a2_3);
                float4 h1v = *reinterpret_cast<const float4*>(&sh1[wid][pp][j]);
                a0_0 = fmaf(w0[j+0], h1v.x, a0_0);
                a0_1 = fmaf(w0[j+1], h1v.y, a0_1);
                a0_2 = fmaf(w0[j+2], h1v.z, a0_2);
                a0_3 = fmaf(w0[j+3], h1v.w, a0_3);
            }
            const float h1n = tanh_fast((a0_0 + a0_1) + (a0_2 + a0_3));
            sh1[wid][cc][lane] = h1n;   // publish h1_t (same-wave in-order DS)

            // --- layer1: a1 = Wih1 @ h1_t
            float a1_0 = 0.f, a1_1 = 0.f, a1_2 = 0.f, a1_3 = 0.f;
#pragma unroll
            for (int j = 0; j < 64; j += 4) {
                float4 h1v = *reinterpret_cast<const float4*>(&sh1[wid][cc][j]);
                a1_0 = fmaf(w1[j+0], h1v.x, a1_0);
                a1_1 = fmaf(w1[j+1], h1v.y, a1_1);
                a1_2 = fmaf(w1[j+2], h1v.z, a1_2);
                a1_3 = fmaf(w1[j+3], h1v.w, a1_3);
            }
            const float h2n = tanh_fast(((a1_0 + a1_1) + (a1_2 + a1_3)) +
                                        ((a2_0 + a2_1) + (a2_2 + a2_3)));
            sh2[wid][cc][lane] = h2n;
        }
    }

    // final h2 is in slot ((T-1)&1)^1 == 0
    // fc1: z[lane] = relu(fc1W[lane,:] @ h2 + fc1b[lane])
    float z;
    {
        const float4* pf = reinterpret_cast<const float4*>(fc1W + lane * 64);
        float s0 = 0.f, s1 = 0.f, s2 = 0.f, s3 = 0.f;
#pragma unroll
        for (int j = 0; j < 16; ++j) {
            float4 wv = pf[j];
            float4 hv = *reinterpret_cast<const float4*>(&sh2[wid][0][4*j]);
            s0 = fmaf(wv.x, hv.x, s0);
            s1 = fmaf(wv.y, hv.y, s1);
            s2 = fmaf(wv.z, hv.z, s2);
            s3 = fmaf(wv.w, hv.w, s3);
        }
        z = fmaxf((s0 + s1) + (s2 + s3) + fc1b[lane], 0.0f);
    }

    // fc2: out[b] = fc2W @ z + fc2b  (wave butterfly reduction)
    float v = fc2W[lane] * z;
#pragma unroll
    for (int off = 32; off; off >>= 1) v += __shfl_xor(v, off);
    if (lane == 0) out[b] = v + fc2b[0];
}

} // namespace

extern "C" void kernel_launch(void* const* d_in, const int* in_sizes, int n_in,
                              void* d_out, int out_size, void* d_ws, size_t ws_size,
                              hipStream_t stream) {
    const float* x    = (const float*)d_in[0];
    const float* Wih0 = (const float*)d_in[1];
    const float* Whh0 = (const float*)d_in[2];
    const float* bih0 = (const float*)d_in[3];
    const float* bhh0 = (const float*)d_in[4];
    const float* Wih1 = (const float*)d_in[5];
    const float* Whh1 = (const float*)d_in[6];
    const float* bih1 = (const float*)d_in[7];
    const float* bhh1 = (const float*)d_in[8];
    const float* fc1W = (const float*)d_in[9];
    const float* fc1b = (const float*)d_in[10];
    const float* fc2W = (const float*)d_in[11];
    const float* fc2b = (const float*)d_in[12];
    float* out = (float*)d_out;

    const int B = in_sizes[0] / T_LEN;          // 4096
    dim3 grid((B + 3) / 4), block(256);
    rnn_fused_kernel<<<grid, block, 0, stream>>>(
        x, Wih0, Whh0, bih0, bhh0, Wih1, Whh1, bih1, bhh1,
        fc1W, fc1b, fc2W, fc2b, out, B);
}

// Round 2
// 373.797 us; speedup vs baseline: 10.2099x; 10.2099x over previous
//
#include <hip/hip_runtime.h>

namespace {

constexpr int T_LEN = 512;

typedef _Float16 half8  __attribute__((ext_vector_type(8)));
typedef float    f32x4v __attribute__((ext_vector_type(4)));
typedef unsigned uint4v __attribute__((ext_vector_type(4)));

#define MFMA16(a, b, c) __builtin_amdgcn_mfma_f32_16x16x32_f16((a), (b), (c), 0, 0, 0)

// In-place pair swap: after this, u = quads [u0,u2,v0,v2], v = [u1,u3,v1,v3]
__device__ __forceinline__ void pswap(unsigned &u, unsigned &v) {
    asm("v_permlane32_swap_b32 %0, %1" : "+v"(u), "+v"(v));
    asm("v_permlane16_swap_b32 %0, %1" : "+v"(u), "+v"(v));
}

// Load an fp16 A-fragment from a row-major 64x64 fp32 matrix, scaled.
// Lane holds A[row, k0 .. k0+7].
__device__ __forceinline__ half8 load_frag(const float* __restrict__ W,
                                           int row, int k0, float s) {
    const float* p = W + row * 64 + k0;
    f32x4v lo = *reinterpret_cast<const f32x4v*>(p);
    f32x4v hi = *reinterpret_cast<const f32x4v*>(p + 4);
    auto c0 = __builtin_amdgcn_cvt_pkrtz(lo.x * s, lo.y * s);
    auto c1 = __builtin_amdgcn_cvt_pkrtz(lo.z * s, lo.w * s);
    auto c2 = __builtin_amdgcn_cvt_pkrtz(hi.x * s, hi.y * s);
    auto c3 = __builtin_amdgcn_cvt_pkrtz(hi.z * s, hi.w * s);
    uint4v u;
    u.x = __builtin_bit_cast(unsigned, c0);
    u.y = __builtin_bit_cast(unsigned, c1);
    u.z = __builtin_bit_cast(unsigned, c2);
    u.w = __builtin_bit_cast(unsigned, c3);
    return __builtin_bit_cast(half8, u);
}

// a holds pre-activation*2; apply tanh(y) = 1 - 2/(exp(2y)+1) elementwise.
__device__ __forceinline__ void tanh4(f32x4v &a) {
#pragma unroll
    for (int q = 0; q < 4; ++q) {
        float e = __expf(a[q]);
        a[q] = 1.0f - 2.0f * __builtin_amdgcn_rcpf(e + 1.0f);
    }
}

// From D-layout h values (hv[t] = h[b, 16t+4g+q], fp32) build next-step
// B-fragments B0 (k=0..31), B1 (k=32..63) via cvt_pkrtz + permlane swaps.
__device__ __forceinline__ void build_frags(const f32x4v hv[4],
                                            half8 &B0, half8 &B1) {
    unsigned hp[4][2];
#pragma unroll
    for (int t = 0; t < 4; ++t) {
        auto a = __builtin_amdgcn_cvt_pkrtz(hv[t].x, hv[t].y);
        auto b = __builtin_amdgcn_cvt_pkrtz(hv[t].z, hv[t].w);
        hp[t][0] = __builtin_bit_cast(unsigned, a);
        hp[t][1] = __builtin_bit_cast(unsigned, b);
    }
    uint4v u0, u1;
    { unsigned u = hp[0][0], v = hp[1][0]; pswap(u, v); u0.x = u; u0.z = v; }
    { unsigned u = hp[0][1], v = hp[1][1]; pswap(u, v); u0.y = u; u0.w = v; }
    { unsigned u = hp[2][0], v = hp[3][0]; pswap(u, v); u1.x = u; u1.z = v; }
    { unsigned u = hp[2][1], v = hp[3][1]; pswap(u, v); u1.y = u; u1.w = v; }
    B0 = __builtin_bit_cast(half8, u0);
    B1 = __builtin_bit_cast(half8, u1);
}

__global__ __launch_bounds__(64, 1)
void rnn_mfma_kernel(const float* __restrict__ x,
                     const float* __restrict__ Wih0,
                     const float* __restrict__ Whh0,
                     const float* __restrict__ bih0,
                     const float* __restrict__ bhh0,
                     const float* __restrict__ Wih1,
                     const float* __restrict__ Whh1,
                     const float* __restrict__ bih1,
                     const float* __restrict__ bhh1,
                     const float* __restrict__ fc1W,
                     const float* __restrict__ fc1b,
                     const float* __restrict__ fc2W,
                     const float* __restrict__ fc2b,
                     float* __restrict__ out)
{
    const int lane   = threadIdx.x;        // 64-thread block = 1 wave
    const int g      = lane >> 4;          // quad 0..3
    const int b16    = lane & 15;          // batch-within-tile / A-row
    const int batch0 = blockIdx.x * 16;

    __shared__ float sx[16 * 68];          // x stage, padded stride 68

    // ---- persistent weight A-fragments (scaled by 2 for tanh folding) ----
    half8 WA0[4][2], WI1[4][2], WH1[4][2];
#pragma unroll
    for (int t = 0; t < 4; ++t)
#pragma unroll
        for (int m = 0; m < 2; ++m) {
            const int row = 16 * t + b16, k0 = 32 * m + 8 * g;
            WA0[t][m] = load_frag(Whh0, row, k0, 2.0f);
            WI1[t][m] = load_frag(Wih1, row, k0, 2.0f);
            WH1[t][m] = load_frag(Whh1, row, k0, 2.0f);
        }

    // biases + layer0 input weight, in D-layout (o = 16t + 4g + q), scaled x2
    f32x4v bb0[4], bb1[4], wx2[4];
#pragma unroll
    for (int t = 0; t < 4; ++t)
#pragma unroll
        for (int q = 0; q < 4; ++q) {
            const int o = 16 * t + 4 * g + q;
            bb0[t][q] = 2.0f * (bih0[o] + bhh0[o]);
            bb1[t][q] = 2.0f * (bih1[o] + bhh1[o]);
            wx2[t][q] = 2.0f * Wih0[o];
        }

    half8 Bh1_0 = {}, Bh1_1 = {};   // h1_{t-1} B-frags (zero at t=0)
    half8 Bh2_0 = {}, Bh2_1 = {};   // h2_{t-1}

    for (int t0 = 0; t0 < T_LEN; t0 += 64) {
        // stage 16 rows x 64 steps of x into LDS (padded stride 68)
        {
            const float* gx = x + (size_t)(batch0 + (lane >> 2)) * T_LEN
                              + t0 + (lane & 3) * 4;
#pragma unroll
            for (int c = 0; c < 4; ++c) {
                f32x4v v = *reinterpret_cast<const f32x4v*>(gx + c * 16);
                *reinterpret_cast<f32x4v*>(
                    &sx[(lane >> 2) * 68 + c * 16 + (lane & 3) * 4]) = v;
            }
        }

#pragma unroll 2
        for (int tt = 0; tt < 64; ++tt) {
            const float xt = sx[b16 * 68 + tt];

            // ---- layer 0: a0 = 2*(x*wx + b) + Whh0' @ h1_prev ----
            f32x4v a0[4];
#pragma unroll
            for (int t = 0; t < 4; ++t) a0[t] = wx2[t] * xt + bb0[t];
#pragma unroll
            for (int t = 0; t < 4; ++t) a0[t] = MFMA16(WA0[t][0], Bh1_0, a0[t]);
#pragma unroll
            for (int t = 0; t < 4; ++t) a0[t] = MFMA16(WA0[t][1], Bh1_1, a0[t]);
#pragma unroll
            for (int t = 0; t < 4; ++t) tanh4(a0[t]);
            build_frags(a0, Bh1_0, Bh1_1);      // h1_t -> B-frags

            // ---- layer 1: a1 = 2*b1 + Wih1' @ h1_t + Whh1' @ h2_prev ----
            f32x4v a1[4];
#pragma unroll
            for (int t = 0; t < 4; ++t) a1[t] = bb1[t];
#pragma unroll
            for (int t = 0; t < 4; ++t) a1[t] = MFMA16(WI1[t][0], Bh1_0, a1[t]);
#pragma unroll
            for (int t = 0; t < 4; ++t) a1[t] = MFMA16(WI1[t][1], Bh1_1, a1[t]);
#pragma unroll
            for (int t = 0; t < 4; ++t) a1[t] = MFMA16(WH1[t][0], Bh2_0, a1[t]);
#pragma unroll
            for (int t = 0; t < 4; ++t) a1[t] = MFMA16(WH1[t][1], Bh2_1, a1[t]);
#pragma unroll
            for (int t = 0; t < 4; ++t) tanh4(a1[t]);
            build_frags(a1, Bh2_0, Bh2_1);      // h2_t -> B-frags
        }
    }

    // ---- epilogue: z = relu(fc1W @ h2 + fc1b); out = fc2W @ z + fc2b ----
    float p = 0.0f;
#pragma unroll
    for (int t = 0; t < 4; ++t) {
        half8 F0 = load_frag(fc1W, 16 * t + b16, 8 * g,      1.0f);
        half8 F1 = load_frag(fc1W, 16 * t + b16, 32 + 8 * g, 1.0f);
        f32x4v z;
#pragma unroll
        for (int q = 0; q < 4; ++q) z[q] = fc1b[16 * t + 4 * g + q];
        z = MFMA16(F0, Bh2_0, z);
        z = MFMA16(F1, Bh2_1, z);
#pragma unroll
        for (int q = 0; q < 4; ++q)
            p += fmaxf(z[q], 0.0f) * fc2W[16 * t + 4 * g + q];
    }
    p += __shfl_xor(p, 16);
    p += __shfl_xor(p, 32);
    if (lane < 16) out[batch0 + lane] = p + fc2b[0];
}

} // namespace

extern "C" void kernel_launch(void* const* d_in, const int* in_sizes, int n_in,
                              void* d_out, int out_size, void* d_ws, size_t ws_size,
                              hipStream_t stream) {
    (void)n_in; (void)out_size; (void)d_ws; (void)ws_size;
    const float* x    = (const float*)d_in[0];
    const float* Wih0 = (const float*)d_in[1];
    const float* Whh0 = (const float*)d_in[2];
    const float* bih0 = (const float*)d_in[3];
    const float* bhh0 = (const float*)d_in[4];
    const float* Wih1 = (const float*)d_in[5];
    const float* Whh1 = (const float*)d_in[6];
    const float* bih1 = (const float*)d_in[7];
    const float* bhh1 = (const float*)d_in[8];
    const float* fc1W = (const float*)d_in[9];
    const float* fc1b = (const float*)d_in[10];
    const float* fc2W = (const float*)d_in[11];
    const float* fc2b = (const float*)d_in[12];
    float* out = (float*)d_out;

    const int B = in_sizes[0] / T_LEN;      // 4096
    dim3 grid(B / 16), block(64);
    rnn_mfma_kernel<<<grid, block, 0, stream>>>(
        x, Wih0, Whh0, bih0, bhh0, Wih1, Whh1, bih1, bhh1,
        fc1W, fc1b, fc2W, fc2b, out);
}

// Round 3
// 143.658 us; speedup vs baseline: 26.5660x; 2.6020x over previous
//
#include <hip/hip_runtime.h>

namespace {

constexpr int T_LEN = 512;
constexpr int XS    = 516;   // padded floats per x-row in LDS (16B-aligned rows, 2-way banks)

typedef _Float16 half8  __attribute__((ext_vector_type(8)));
typedef float    f32x4v __attribute__((ext_vector_type(4)));
typedef unsigned uint2v __attribute__((ext_vector_type(2)));
typedef unsigned uint4v __attribute__((ext_vector_type(4)));

#define MFMA16(a, b, c) __builtin_amdgcn_mfma_f32_16x16x32_f16((a), (b), (c), 0, 0, 0)

// Load an fp16 A-fragment from a row-major 64x64 fp32 matrix, scaled.
// Lane holds A[row, k0 .. k0+7].
__device__ __forceinline__ half8 load_frag(const float* __restrict__ W,
                                           int row, int k0, float s) {
    const float* p = W + row * 64 + k0;
    f32x4v lo = *reinterpret_cast<const f32x4v*>(p);
    f32x4v hi = *reinterpret_cast<const f32x4v*>(p + 4);
    uint4v u;
    u.x = __builtin_bit_cast(unsigned, __builtin_amdgcn_cvt_pkrtz(lo.x * s, lo.y * s));
    u.y = __builtin_bit_cast(unsigned, __builtin_amdgcn_cvt_pkrtz(lo.z * s, lo.w * s));
    u.z = __builtin_bit_cast(unsigned, __builtin_amdgcn_cvt_pkrtz(hi.x * s, hi.y * s));
    u.w = __builtin_bit_cast(unsigned, __builtin_amdgcn_cvt_pkrtz(hi.z * s, hi.w * s));
    return __builtin_bit_cast(half8, u);
}

// a holds pre-activation*2; tanh(y) = 1 - 2/(exp(2y)+1), robust at +-inf.
__device__ __forceinline__ void tanh4(f32x4v &a) {
#pragma unroll
    for (int q = 0; q < 4; ++q) {
        float e = __expf(a[q]);
        a[q] = 1.0f - 2.0f * __builtin_amdgcn_rcpf(e + 1.0f);
    }
}

__global__ __launch_bounds__(256, 2)
void rnn_mfma4_kernel(const float* __restrict__ x,
                      const float* __restrict__ Wih0,
                      const float* __restrict__ Whh0,
                      const float* __restrict__ bih0,
                      const float* __restrict__ bhh0,
                      const float* __restrict__ Wih1,
                      const float* __restrict__ Whh1,
                      const float* __restrict__ bih1,
                      const float* __restrict__ bhh1,
                      const float* __restrict__ fc1W,
                      const float* __restrict__ fc1b,
                      const float* __restrict__ fc2W,
                      const float* __restrict__ fc2b,
                      float* __restrict__ out)
{
    const int tid    = threadIdx.x;
    const int wv     = tid >> 6;        // wave 0..3: owns output rows 16wv..16wv+15
    const int lane   = tid & 63;
    const int g      = lane >> 4;
    const int b16    = lane & 15;       // batch within tile
    const int batch0 = blockIdx.x * 16;

    __shared__ float    sx[16 * XS];        // whole x tile, staged once
    __shared__ _Float16 sh1[2][16][72];     // h1 exchange, ping-pong, padded
    __shared__ _Float16 sh2[2][16][72];     // h2 exchange
    __shared__ float    pf[4][16];          // fc2 partials

    // ---- stage x[batch0..+15][0..511] into LDS (coalesced f32x4) ----
    {
        const float* gx = x + (size_t)batch0 * T_LEN;
#pragma unroll
        for (int c = 0; c < 8; ++c) {
            int idx = tid + c * 256;            // float4 index 0..2047
            int r = idx >> 7, c4 = idx & 127;   // 128 float4 per row
            f32x4v v = *reinterpret_cast<const f32x4v*>(gx + r * T_LEN + c4 * 4);
            *reinterpret_cast<f32x4v*>(&sx[r * XS + c4 * 4]) = v;
        }
    }

    // ---- per-wave persistent weights (x2 scale folds tanh's 2y) ----
    const int row = 16 * wv + b16;
    const half8 WA0_0 = load_frag(Whh0, row,      8 * g, 2.0f);
    const half8 WA0_1 = load_frag(Whh0, row, 32 + 8 * g, 2.0f);
    const half8 WI1_0 = load_frag(Wih1, row,      8 * g, 2.0f);
    const half8 WI1_1 = load_frag(Wih1, row, 32 + 8 * g, 2.0f);
    const half8 WH1_0 = load_frag(Whh1, row,      8 * g, 2.0f);
    const half8 WH1_1 = load_frag(Whh1, row, 32 + 8 * g, 2.0f);

    f32x4v bb0, bb1, wx2;
#pragma unroll
    for (int q = 0; q < 4; ++q) {
        const int o = 16 * wv + 4 * g + q;      // D-layout row this lane owns
        bb0[q] = 2.0f * (bih0[o] + bhh0[o]);
        bb1[q] = 2.0f * (bih1[o] + bhh1[o]);
        wx2[q] = 2.0f * Wih0[o];
    }
    const int o2 = 16 * wv + 4 * g;             // half-offset for publish

    // publish 4 f32 -> 4 halves at h[b16][o2..o2+3]
    auto publish = [&](_Float16* base, const f32x4v& a) {
        uint2v p;
        p.x = __builtin_bit_cast(unsigned, __builtin_amdgcn_cvt_pkrtz(a[0], a[1]));
        p.y = __builtin_bit_cast(unsigned, __builtin_amdgcn_cvt_pkrtz(a[2], a[3]));
        *reinterpret_cast<uint2v*>(base + b16 * 72 + o2) = p;
    };
    auto rdfrag = [&](const _Float16* base, int k0) -> half8 {
        return *reinterpret_cast<const half8*>(base + b16 * 72 + k0);
    };

    half8 Bh1_0, Bh1_1, Bh2_0, Bh2_1;

    __syncthreads();                            // x staged

    float xt = sx[b16 * XS + 0];
    float xn = sx[b16 * XS + 1];

    // ---- peel k=0: h1(0) = tanh(2(wx*x0 + b0)); h2(-1) = 0 ----
    {
        f32x4v a0 = wx2 * xt + bb0;
        tanh4(a0);
        publish(&sh1[0][0][0], a0);
        *reinterpret_cast<uint2v*>(&sh2[0][0][0] + b16 * 72 + o2) = uint2v{0, 0};
        __syncthreads();
        Bh1_0 = rdfrag(&sh1[0][0][0],      8 * g);
        Bh1_1 = rdfrag(&sh1[0][0][0], 32 + 8 * g);
        Bh2_0 = rdfrag(&sh2[0][0][0],      8 * g);
        Bh2_1 = rdfrag(&sh2[0][0][0], 32 + 8 * g);
        xt = xn; xn = sx[b16 * XS + 2];
    }

    // ---- main: iter k computes h1(k) and h2(k-1); one barrier per step ----
#pragma unroll 2
    for (int k = 1; k < T_LEN; ++k) {
        const int s = k & 1;
        const float xf = sx[b16 * XS + k + 2];   // prefetch (pad covers k=511)

        f32x4v a0 = wx2 * xt + bb0;              // layer0, this wave's 16 rows
        a0 = MFMA16(WA0_0, Bh1_0, a0);
        a0 = MFMA16(WA0_1, Bh1_1, a0);

        f32x4v zz = {};
        f32x4v u  = MFMA16(WI1_0, Bh1_0, bb1);   // layer1 as two parallel 2-chains
        u  = MFMA16(WI1_1, Bh1_1, u);
        f32x4v v4 = MFMA16(WH1_0, Bh2_0, zz);
        v4 = MFMA16(WH1_1, Bh2_1, v4);
        f32x4v a1 = u + v4;

        tanh4(a0);
        tanh4(a1);
        publish(&sh1[s][0][0], a0);              // h1(k)
        publish(&sh2[s][0][0], a1);              // h2(k-1)
        __syncthreads();
        Bh1_0 = rdfrag(&sh1[s][0][0],      8 * g);
        Bh1_1 = rdfrag(&sh1[s][0][0], 32 + 8 * g);
        Bh2_0 = rdfrag(&sh2[s][0][0],      8 * g);
        Bh2_1 = rdfrag(&sh2[s][0][0], 32 + 8 * g);
        xt = xn; xn = xf;
    }

    // ---- epilogue: h2(511) from h1(511), h2(510) ----
    {
        f32x4v zz = {};
        f32x4v u  = MFMA16(WI1_0, Bh1_0, bb1);
        u  = MFMA16(WI1_1, Bh1_1, u);
        f32x4v v4 = MFMA16(WH1_0, Bh2_0, zz);
        v4 = MFMA16(WH1_1, Bh2_1, v4);
        f32x4v a1 = u + v4;
        tanh4(a1);
        publish(&sh2[0][0][0], a1);
        __syncthreads();
        Bh2_0 = rdfrag(&sh2[0][0][0],      8 * g);
        Bh2_1 = rdfrag(&sh2[0][0][0], 32 + 8 * g);
    }

    // ---- fc1 (wave's 16 rows) + relu + fc2 dot ----
    const half8 F0 = load_frag(fc1W, row,      8 * g, 1.0f);
    const half8 F1 = load_frag(fc1W, row, 32 + 8 * g, 1.0f);
    f32x4v zf;
#pragma unroll
    for (int q = 0; q < 4; ++q) zf[q] = fc1b[16 * wv + 4 * g + q];
    zf = MFMA16(F0, Bh2_0, zf);
    zf = MFMA16(F1, Bh2_1, zf);

    float pacc = 0.0f;
#pragma unroll
    for (int q = 0; q < 4; ++q)
        pacc += fmaxf(zf[q], 0.0f) * fc2W[16 * wv + 4 * g + q];
    pacc += __shfl_xor(pacc, 16);
    pacc += __shfl_xor(pacc, 32);
    if (lane < 16) pf[wv][lane] = pacc;
    __syncthreads();
    if (tid < 16)
        out[batch0 + tid] = pf[0][tid] + pf[1][tid] + pf[2][tid] + pf[3][tid]
                          + fc2b[0];
}

} // namespace

extern "C" void kernel_launch(void* const* d_in, const int* in_sizes, int n_in,
                              void* d_out, int out_size, void* d_ws, size_t ws_size,
                              hipStream_t stream) {
    (void)n_in; (void)out_size; (void)d_ws; (void)ws_size;
    const float* x    = (const float*)d_in[0];
    const float* Wih0 = (const float*)d_in[1];
    const float* Whh0 = (const float*)d_in[2];
    const float* bih0 = (const float*)d_in[3];
    const float* bhh0 = (const float*)d_in[4];
    const float* Wih1 = (const float*)d_in[5];
    const float* Whh1 = (const float*)d_in[6];
    const float* bih1 = (const float*)d_in[7];
    const float* bhh1 = (const float*)d_in[8];
    const float* fc1W = (const float*)d_in[9];
    const float* fc1b = (const float*)d_in[10];
    const float* fc2W = (const float*)d_in[11];
    const float* fc2b = (const float*)d_in[12];
    float* out = (float*)d_out;

    const int B = in_sizes[0] / T_LEN;      // 4096
    dim3 grid(B / 16), block(256);
    rnn_mfma4_kernel<<<grid, block, 0, stream>>>(
        x, Wih0, Whh0, bih0, bhh0, Wih1, Whh1, bih1, bhh1,
        fc1W, fc1b, fc2W, fc2b, out);
}